// Round 4
// baseline (758.120 us; speedup 1.0000x reference)
//
#include <hip/hip_runtime.h>
#include <hip/hip_bf16.h>

#define NN 50000      // nodes
#define NE 800000     // edges
#define NR 500        // relations
#define KEH 256       // input feat dim
#define KRH 128       // proj feat dim

typedef __attribute__((ext_vector_type(8))) __bf16 bf16x8;
typedef __attribute__((ext_vector_type(4))) float f32x4;

// ---- workspace layout (bytes, 16B aligned), total ~29.3 MiB ----
#define OFF_XH     0UL            // [NN][128] bf16  12,800,000
#define OFF_XT     12800000UL     // [NN][128] bf16  12,800,000
#define OFF_SP     25600000UL     // [NN] float4 (s_hh0,s_hh1,s_th0,s_th1)
#define OFF_DP     26400000UL     // [NN] float4 (s_tt0,s_tt1,s_ht0,s_ht1)
#define OFF_SUMS   27200000UL     // [NR] float4 softmax denominators (8000 B)
#define OFF_CNT    27208000UL     // [NR] u32 counts (contiguous after sums)
#define OFF_BASE   27210048UL     // [NR+1] u32 segment bases
#define OFF_CUR    27212096UL     // [NR] u32 scatter cursors
#define OFF_ELIST  27214144UL     // [NE] u32 edge ids bucketed by rel
#define OFF_ACC    30414144UL     // [NR][128] f32 accumulator
#define OFF_AH     30670144UL     // [256] f32 a_h
#define OFF_AT     30671168UL     // [256] f32 a_t
#define OFF_FLAG   30672192UL     // u32: 1 = inputs are bf16, 0 = f32

__device__ __forceinline__ int clampi(int v, int hi) {  // [0, hi)
    v = v < 0 ? 0 : v;
    return v >= hi ? hi - 1 : v;
}

// block0: sniff input dtype from x_e bit patterns + convert a_h/a_t to f32.
// blocks 1..: zero sums+counts (2500 u32) and acc (64000 u32).
__global__ __launch_bounds__(256) void k_init(const unsigned* __restrict__ xe_raw,
                                              const void* __restrict__ ah_in, const void* __restrict__ at_in,
                                              unsigned* __restrict__ flag, float* __restrict__ ah32,
                                              float* __restrict__ at32,
                                              unsigned* __restrict__ sums_cnt, unsigned* __restrict__ accz) {
    if (blockIdx.x == 0) {
        __shared__ int votes;
        int t = threadIdx.x;
        if (t == 0) votes = 0;
        __syncthreads();
        if (t < 64) {
            // low u16 of each 32-bit word: uniform mantissa bits if x_e is f32
            // (~6% hit rate below); an N(0,1) bf16 value (exp ~127) if bf16.
            unsigned w = xe_raw[t];
            unsigned ex = (w >> 7) & 0xFFu;
            if (ex >= 115u && ex <= 131u) atomicAdd(&votes, 1);
        }
        __syncthreads();
        int isbf = votes >= 32;
        if (t == 0) flag[0] = (unsigned)isbf;
        if (t < 256) {
            ah32[t] = isbf ? __bfloat162float(((const __hip_bfloat16*)ah_in)[t]) : ((const float*)ah_in)[t];
            at32[t] = isbf ? __bfloat162float(((const __hip_bfloat16*)at_in)[t]) : ((const float*)at_in)[t];
        }
    } else {
        int stride = (gridDim.x - 1) * 256;
        int t0 = (blockIdx.x - 1) * 256 + threadIdx.x;
        for (int i = t0; i < 2500; i += stride) sums_cnt[i] = 0u;
        for (int i = t0; i < NR * KRH; i += stride) accz[i] = 0u;
    }
}

// C[m,n] = sum_k A[m,k] * W[n,k] for W in {w_h,w_t}; A = x_e (f32 or bf16).
// f32 inputs use split-bf16: x ~= hi + lo, 3 MFMA passes -> ~f32 accuracy.
// 256 thr = 4 waves; block tile 64 rows x 128 cols; wave tile 16 x 128.
__global__ __launch_bounds__(256) void k_gemm(const void* __restrict__ xe,
                                              const void* __restrict__ wh,
                                              const void* __restrict__ wt,
                                              const unsigned* __restrict__ flag,
                                              __hip_bfloat16* __restrict__ xh, __hip_bfloat16* __restrict__ xt) {
    const int isbf = (int)flag[0];
    int wave = threadIdx.x >> 6;
    int lane = threadIdx.x & 63;
    int quad = lane >> 4;
    int l16  = lane & 15;
    int rowBase = blockIdx.x * 64 + wave * 16;
    int arow = rowBase + l16;
    if (arow >= NN) arow = NN - 1;   // clamp; OOB rows never stored

    f32x4 accH[8], accT[8];
    for (int t = 0; t < 8; ++t) { accH[t] = (f32x4){0.f,0.f,0.f,0.f}; accT[t] = (f32x4){0.f,0.f,0.f,0.f}; }

    for (int ks = 0; ks < 8; ++ks) {
        int kb = ks * 32 + quad * 8;
        bf16x8 a_hi, a_lo;
        if (isbf) {
            a_hi = *(const bf16x8*)((const __hip_bfloat16*)xe + (size_t)arow * KEH + kb);
        } else {
            const float* p = (const float*)xe + (size_t)arow * KEH + kb;
            float4 v0 = *(const float4*)p, v1 = *(const float4*)(p + 4);
            float v[8] = {v0.x, v0.y, v0.z, v0.w, v1.x, v1.y, v1.z, v1.w};
            for (int j = 0; j < 8; ++j) {
                __bf16 h = (__bf16)v[j];
                a_hi[j] = h;
                a_lo[j] = (__bf16)(v[j] - (float)h);
            }
        }
        for (int ct = 0; ct < 8; ++ct) {
            int wr = ct * 16 + l16;
            size_t widx = (size_t)wr * KEH + kb;
            bf16x8 bh_hi, bh_lo, bt_hi, bt_lo;
            if (isbf) {
                bh_hi = *(const bf16x8*)((const __hip_bfloat16*)wh + widx);
                bt_hi = *(const bf16x8*)((const __hip_bfloat16*)wt + widx);
            } else {
                const float* ph = (const float*)wh + widx;
                const float* pt = (const float*)wt + widx;
                float4 h0 = *(const float4*)ph, h1 = *(const float4*)(ph + 4);
                float4 t0 = *(const float4*)pt, t1 = *(const float4*)(pt + 4);
                float vh[8] = {h0.x, h0.y, h0.z, h0.w, h1.x, h1.y, h1.z, h1.w};
                float vt[8] = {t0.x, t0.y, t0.z, t0.w, t1.x, t1.y, t1.z, t1.w};
                for (int j = 0; j < 8; ++j) {
                    __bf16 hh = (__bf16)vh[j], ht = (__bf16)vt[j];
                    bh_hi[j] = hh; bh_lo[j] = (__bf16)(vh[j] - (float)hh);
                    bt_hi[j] = ht; bt_lo[j] = (__bf16)(vt[j] - (float)ht);
                }
            }
            accH[ct] = __builtin_amdgcn_mfma_f32_16x16x32_bf16(a_hi, bh_hi, accH[ct], 0, 0, 0);
            accT[ct] = __builtin_amdgcn_mfma_f32_16x16x32_bf16(a_hi, bt_hi, accT[ct], 0, 0, 0);
            if (!isbf) {   // wave-uniform branch
                accH[ct] = __builtin_amdgcn_mfma_f32_16x16x32_bf16(a_lo, bh_hi, accH[ct], 0, 0, 0);
                accH[ct] = __builtin_amdgcn_mfma_f32_16x16x32_bf16(a_hi, bh_lo, accH[ct], 0, 0, 0);
                accT[ct] = __builtin_amdgcn_mfma_f32_16x16x32_bf16(a_lo, bt_hi, accT[ct], 0, 0, 0);
                accT[ct] = __builtin_amdgcn_mfma_f32_16x16x32_bf16(a_hi, bt_lo, accT[ct], 0, 0, 0);
            }
        }
    }
    // C/D layout: col = lane&15, row = quad*4 + reg   [m89-verified]
    for (int ct = 0; ct < 8; ++ct) {
        int col = ct * 16 + l16;
        for (int r2 = 0; r2 < 4; ++r2) {
            int orow = rowBase + quad * 4 + r2;
            if (orow < NN) {
                xh[(size_t)orow * KRH + col] = __float2bfloat16(accH[ct][r2]);
                xt[(size_t)orow * KRH + col] = __float2bfloat16(accT[ct][r2]);
            }
        }
    }
}

// One wave per node: 8 dot products of length 128.
__global__ __launch_bounds__(256) void k_scores(const __hip_bfloat16* __restrict__ xh,
                                                const __hip_bfloat16* __restrict__ xt,
                                                const float* __restrict__ ah, const float* __restrict__ at,
                                                float4* __restrict__ sp, float4* __restrict__ dp) {
    int lane = threadIdx.x & 63;
    int w = threadIdx.x >> 6;
    int n = blockIdx.x * 4 + w;
    if (n >= NN) return;
    float xh0 = __bfloat162float(xh[(size_t)n*KRH + lane]);
    float xh1 = __bfloat162float(xh[(size_t)n*KRH + 64 + lane]);
    float xt0 = __bfloat162float(xt[(size_t)n*KRH + lane]);
    float xt1 = __bfloat162float(xt[(size_t)n*KRH + 64 + lane]);
    float ah00 = ah[lane],       ah01 = ah[64 + lane];
    float ah10 = ah[128 + lane], ah11 = ah[192 + lane];
    float at00 = at[lane],       at01 = at[64 + lane];
    float at10 = at[128 + lane], at11 = at[192 + lane];
    float v[8];
    v[0] = xh0*ah00 + xh1*ah01;  // s_hh h0
    v[1] = xh0*ah10 + xh1*ah11;  // s_hh h1
    v[2] = xt0*ah00 + xt1*ah01;  // s_th h0
    v[3] = xt0*ah10 + xt1*ah11;  // s_th h1
    v[4] = xt0*at00 + xt1*at01;  // s_tt h0
    v[5] = xt0*at10 + xt1*at11;  // s_tt h1
    v[6] = xh0*at00 + xh1*at01;  // s_ht h0
    v[7] = xh0*at10 + xh1*at11;  // s_ht h1
    for (int off = 32; off; off >>= 1)
        for (int j = 0; j < 8; ++j) v[j] += __shfl_xor(v[j], off);
    if (lane == 0) {
        sp[n] = make_float4(v[0], v[1], v[2], v[3]);
        dp[n] = make_float4(v[4], v[5], v[6], v[7]);
    }
}

__device__ __forceinline__ float eexp(float x) {
    x = x > 0.f ? x : 0.01f * x;       // leaky_relu(0.01)
    x = fminf(x, 50.f);                // overflow guard
    return __expf(x);
}

// Per edge: 4 exp scores -> LDS-staged segment sums + per-rel histogram.
__global__ __launch_bounds__(256) void k_edge(const int* __restrict__ src, const int* __restrict__ dst,
                                              const int* __restrict__ rel,
                                              const float4* __restrict__ sp, const float4* __restrict__ dp,
                                              float* __restrict__ sums, unsigned* __restrict__ counts) {
    __shared__ float ls[NR * 4];
    __shared__ unsigned lc[NR];
    for (int i = threadIdx.x; i < NR * 4; i += 256) ls[i] = 0.f;
    for (int i = threadIdx.x; i < NR; i += 256) lc[i] = 0u;
    __syncthreads();
    int stride = gridDim.x * blockDim.x;
    for (int e = blockIdx.x * blockDim.x + threadIdx.x; e < NE; e += stride) {
        int s = clampi(src[e], NN), d = clampi(dst[e], NN), r = clampi(rel[e], NR);
        float4 a = sp[s], b = dp[d];
        atomicAdd(&ls[r*4+0], eexp(a.x + b.x));
        atomicAdd(&ls[r*4+1], eexp(a.y + b.y));
        atomicAdd(&ls[r*4+2], eexp(a.z + b.z));
        atomicAdd(&ls[r*4+3], eexp(a.w + b.w));
        atomicAdd(&lc[r], 1u);
    }
    __syncthreads();
    for (int i = threadIdx.x; i < NR * 4; i += 256)
        if (ls[i] != 0.f) atomicAdd(&sums[i], ls[i]);
    for (int i = threadIdx.x; i < NR; i += 256)
        if (lc[i]) atomicAdd(&counts[i], lc[i]);
}

// Single-block exclusive scan of counts[500] -> base, cursor.
__global__ __launch_bounds__(512) void k_scan(const unsigned* __restrict__ counts,
                                              unsigned* __restrict__ base, unsigned* __restrict__ cursor) {
    __shared__ unsigned sc[512];
    int t = threadIdx.x;
    sc[t] = (t < NR) ? counts[t] : 0u;
    __syncthreads();
    for (int off = 1; off < 512; off <<= 1) {
        unsigned add = (t >= off) ? sc[t - off] : 0u;
        __syncthreads();
        sc[t] += add;
        __syncthreads();
    }
    if (t < NR) {
        unsigned b = (t == 0) ? 0u : sc[t - 1];
        base[t] = b;
        cursor[t] = b;
    }
    if (t == NR) base[NR] = sc[NR - 1];
}

__global__ __launch_bounds__(256) void k_scatter(const int* __restrict__ rel,
                                                 unsigned* __restrict__ cursor, unsigned* __restrict__ elist) {
    int stride = gridDim.x * blockDim.x;
    for (int e = blockIdx.x * blockDim.x + threadIdx.x; e < NE; e += stride) {
        int r = clampi(rel[e], NR);
        unsigned pos = atomicAdd(&cursor[r], 1u);
        if (pos < NE) elist[pos] = (unsigned)e;
    }
}

// 32 blocks per rel, 128 threads (thread = column). Register accumulation, exp
// recomputed from sp/dp (L2-resident); one global fadd per (block,col) at end.
#define PB 32  // blocks per relation
__global__ __launch_bounds__(128) void k_acc(const int* __restrict__ src, const int* __restrict__ dst,
                                             const float4* __restrict__ sp, const float4* __restrict__ dp,
                                             const float4* __restrict__ sums4,
                                             const unsigned* __restrict__ counts, const unsigned* __restrict__ base,
                                             const unsigned* __restrict__ elist,
                                             const __hip_bfloat16* __restrict__ xh,
                                             const __hip_bfloat16* __restrict__ xt,
                                             float* __restrict__ acc) {
    int r = blockIdx.x / PB;
    int p = blockIdx.x % PB;
    int col = threadIdx.x;
    unsigned cnt = counts[r];
    if (cnt > NE) cnt = 0;            // poison guard
    unsigned b0 = base[r];
    float4 s = sums4[r];
    float inv0 = 1.f/(s.x + 1e-16f), inv1 = 1.f/(s.y + 1e-16f);
    float inv2 = 1.f/(s.z + 1e-16f), inv3 = 1.f/(s.w + 1e-16f);
    float a = 0.f;
    unsigned i = (unsigned)p;
    if (i < cnt) {
        unsigned e = elist[b0 + i];
        int sn = clampi(src[e], NN), dn = clampi(dst[e], NN);
        float4 av = sp[sn], bv = dp[dn];
        for (;;) {
            unsigned in = i + PB;
            bool more = in < cnt;
            int sn2 = 0, dn2 = 0; float4 av2 = make_float4(0,0,0,0), bv2 = av2;
            if (more) {                      // prefetch next edge's whole score path
                unsigned e2 = elist[b0 + in];
                sn2 = clampi(src[e2], NN); dn2 = clampi(dst[e2], NN);
                av2 = sp[sn2]; bv2 = dp[dn2];
            }
            float w1 = eexp(av.x + bv.x) * inv0 + eexp(av.y + bv.y) * inv1;
            float w2 = eexp(av.z + bv.z) * inv2 + eexp(av.w + bv.w) * inv3;
            a = fmaf(w1, __bfloat162float(xh[(size_t)sn*KRH + col]), a);
            a = fmaf(w2, __bfloat162float(xt[(size_t)dn*KRH + col]), a);
            if (!more) break;
            i = in; sn = sn2; dn = dn2; av = av2; bv = bv2;
        }
    }
    atomicAdd(&acc[(size_t)r*KRH + col], a);
}

// Output dtype follows input dtype (reference returns x_e.dtype).
__global__ __launch_bounds__(256) void k_out(const float* __restrict__ acc,
                                             const unsigned* __restrict__ flag, void* __restrict__ out) {
    int i = blockIdx.x * 256 + threadIdx.x;
    if (i < NR * KRH) {
        float v = acc[i] * 0.25f;     // / num_heads(2) / 2
        if (!isfinite(v)) v = 0.f;    // diagnostic backstop
        if (flag[0]) ((__hip_bfloat16*)out)[i] = __float2bfloat16(v);
        else         ((float*)out)[i] = v;
    }
}

extern "C" void kernel_launch(void* const* d_in, const int* in_sizes, int n_in,
                              void* d_out, int out_size, void* d_ws, size_t ws_size,
                              hipStream_t stream) {
    const void* xe  = d_in[0];
    const int* eidx = (const int*)d_in[1];
    const int* rel  = (const int*)d_in[2];
    const void* wh  = d_in[3];
    const void* wt  = d_in[4];
    const void* ahp = d_in[5];
    const void* atp = d_in[6];

    const int* src = eidx;
    const int* dst = eidx + NE;

    char* ws = (char*)d_ws;
    __hip_bfloat16* xh = (__hip_bfloat16*)(ws + OFF_XH);
    __hip_bfloat16* xt = (__hip_bfloat16*)(ws + OFF_XT);
    float4*   sp     = (float4*)(ws + OFF_SP);
    float4*   dp     = (float4*)(ws + OFF_DP);
    float*    sums   = (float*)(ws + OFF_SUMS);
    unsigned* counts = (unsigned*)(ws + OFF_CNT);
    unsigned* basep  = (unsigned*)(ws + OFF_BASE);
    unsigned* cursor = (unsigned*)(ws + OFF_CUR);
    unsigned* elist  = (unsigned*)(ws + OFF_ELIST);
    float*    acc    = (float*)(ws + OFF_ACC);
    float*    ah32   = (float*)(ws + OFF_AH);
    float*    at32   = (float*)(ws + OFF_AT);
    unsigned* flag   = (unsigned*)(ws + OFF_FLAG);

    k_init<<<261, 256, 0, stream>>>((const unsigned*)xe, ahp, atp, flag, ah32, at32,
                                     (unsigned*)(ws + OFF_SUMS), (unsigned*)acc);
    k_gemm<<<(NN + 63) / 64, 256, 0, stream>>>(xe, wh, wt, flag, xh, xt);
    k_scores<<<(NN + 3) / 4, 256, 0, stream>>>(xh, xt, ah32, at32, sp, dp);
    k_edge<<<512, 256, 0, stream>>>(src, dst, rel, sp, dp, sums, counts);
    k_scan<<<1, 512, 0, stream>>>(counts, basep, cursor);
    k_scatter<<<512, 256, 0, stream>>>(rel, cursor, elist);
    k_acc<<<NR * PB, 128, 0, stream>>>(src, dst, sp, dp, (const float4*)sums, counts, basep, elist, xh, xt, acc);
    k_out<<<(NR * KRH + 255) / 256, 256, 0, stream>>>(acc, flag, d_out);
}

// Round 5
// 414.831 us; speedup vs baseline: 1.8275x; 1.8275x over previous
//
#include <hip/hip_runtime.h>
#include <hip/hip_bf16.h>

#define NN 50000      // nodes
#define NE 800000     // edges
#define NR 500        // relations
#define KEH 256       // input feat dim
#define KRH 128       // proj feat dim

typedef __attribute__((ext_vector_type(8))) __bf16 bf16x8;
typedef __attribute__((ext_vector_type(4))) float f32x4;

// ---- workspace layout (bytes, 16B aligned), total ~29.3 MiB ----
#define OFF_XH     0UL            // [NN][128] bf16  12,800,000
#define OFF_XT     12800000UL     // [NN][128] bf16  12,800,000
#define OFF_SP     25600000UL     // [NN] float4 (s_hh0,s_hh1,s_th0,s_th1)
#define OFF_DP     26400000UL     // [NN] float4 (s_tt0,s_tt1,s_ht0,s_ht1)
#define OFF_SUMS   27200000UL     // [NR] float4 softmax denominators (8000 B)
#define OFF_CNT    27208000UL     // [NR] u32 counts (contiguous after sums)
#define OFF_BASE   27210048UL     // [NR+1] u32 segment bases
#define OFF_CUR    27212096UL     // [NR] u32 scatter cursors
#define OFF_ELIST  27214144UL     // [NE] u32 edge ids bucketed by rel
#define OFF_ACC    30414144UL     // [NR][128] f32 accumulator
#define OFF_AH     30670144UL     // [256] f32 a_h
#define OFF_AT     30671168UL     // [256] f32 a_t
#define OFF_FLAG   30672192UL     // u32: 1 = inputs are bf16, 0 = f32

__device__ __forceinline__ int clampi(int v, int hi) {  // [0, hi)
    v = v < 0 ? 0 : v;
    return v >= hi ? hi - 1 : v;
}

// block0: sniff input dtype from x_e bit patterns + convert a_h/a_t to f32.
// blocks 1..: zero sums+counts (2500 u32) and acc (64000 u32).
__global__ __launch_bounds__(256) void k_init(const unsigned* __restrict__ xe_raw,
                                              const void* __restrict__ ah_in, const void* __restrict__ at_in,
                                              unsigned* __restrict__ flag, float* __restrict__ ah32,
                                              float* __restrict__ at32,
                                              unsigned* __restrict__ sums_cnt, unsigned* __restrict__ accz) {
    if (blockIdx.x == 0) {
        __shared__ int votes;
        int t = threadIdx.x;
        if (t == 0) votes = 0;
        __syncthreads();
        if (t < 64) {
            // low u16 of each 32-bit word: uniform mantissa bits if x_e is f32
            // (~6% hit rate below); an N(0,1) bf16 value (exp ~127) if bf16.
            unsigned w = xe_raw[t];
            unsigned ex = (w >> 7) & 0xFFu;
            if (ex >= 115u && ex <= 131u) atomicAdd(&votes, 1);
        }
        __syncthreads();
        int isbf = votes >= 32;
        if (t == 0) flag[0] = (unsigned)isbf;
        if (t < 256) {
            ah32[t] = isbf ? __bfloat162float(((const __hip_bfloat16*)ah_in)[t]) : ((const float*)ah_in)[t];
            at32[t] = isbf ? __bfloat162float(((const __hip_bfloat16*)at_in)[t]) : ((const float*)at_in)[t];
        }
    } else {
        int stride = (gridDim.x - 1) * 256;
        int t0 = (blockIdx.x - 1) * 256 + threadIdx.x;
        for (int i = t0; i < 2500; i += stride) sums_cnt[i] = 0u;
        for (int i = t0; i < NR * KRH; i += stride) accz[i] = 0u;
    }
}

// C[m,n] = sum_k A[m,k] * W[n,k] for W in {w_h,w_t}; A = x_e (f32 or bf16).
// f32 inputs use split-bf16: x ~= hi + lo, 3 MFMA passes -> ~f32 accuracy.
__global__ __launch_bounds__(256) void k_gemm(const void* __restrict__ xe,
                                              const void* __restrict__ wh,
                                              const void* __restrict__ wt,
                                              const unsigned* __restrict__ flag,
                                              __hip_bfloat16* __restrict__ xh, __hip_bfloat16* __restrict__ xt) {
    const int isbf = (int)flag[0];
    int wave = threadIdx.x >> 6;
    int lane = threadIdx.x & 63;
    int quad = lane >> 4;
    int l16  = lane & 15;
    int rowBase = blockIdx.x * 64 + wave * 16;
    int arow = rowBase + l16;
    if (arow >= NN) arow = NN - 1;   // clamp; OOB rows never stored

    f32x4 accH[8], accT[8];
    for (int t = 0; t < 8; ++t) { accH[t] = (f32x4){0.f,0.f,0.f,0.f}; accT[t] = (f32x4){0.f,0.f,0.f,0.f}; }

    for (int ks = 0; ks < 8; ++ks) {
        int kb = ks * 32 + quad * 8;
        bf16x8 a_hi, a_lo;
        if (isbf) {
            a_hi = *(const bf16x8*)((const __hip_bfloat16*)xe + (size_t)arow * KEH + kb);
        } else {
            const float* p = (const float*)xe + (size_t)arow * KEH + kb;
            float4 v0 = *(const float4*)p, v1 = *(const float4*)(p + 4);
            float v[8] = {v0.x, v0.y, v0.z, v0.w, v1.x, v1.y, v1.z, v1.w};
            for (int j = 0; j < 8; ++j) {
                __bf16 h = (__bf16)v[j];
                a_hi[j] = h;
                a_lo[j] = (__bf16)(v[j] - (float)h);
            }
        }
        for (int ct = 0; ct < 8; ++ct) {
            int wr = ct * 16 + l16;
            size_t widx = (size_t)wr * KEH + kb;
            bf16x8 bh_hi, bh_lo, bt_hi, bt_lo;
            if (isbf) {
                bh_hi = *(const bf16x8*)((const __hip_bfloat16*)wh + widx);
                bt_hi = *(const bf16x8*)((const __hip_bfloat16*)wt + widx);
            } else {
                const float* ph = (const float*)wh + widx;
                const float* pt = (const float*)wt + widx;
                float4 h0 = *(const float4*)ph, h1 = *(const float4*)(ph + 4);
                float4 t0 = *(const float4*)pt, t1 = *(const float4*)(pt + 4);
                float vh[8] = {h0.x, h0.y, h0.z, h0.w, h1.x, h1.y, h1.z, h1.w};
                float vt[8] = {t0.x, t0.y, t0.z, t0.w, t1.x, t1.y, t1.z, t1.w};
                for (int j = 0; j < 8; ++j) {
                    __bf16 hh = (__bf16)vh[j], ht = (__bf16)vt[j];
                    bh_hi[j] = hh; bh_lo[j] = (__bf16)(vh[j] - (float)hh);
                    bt_hi[j] = ht; bt_lo[j] = (__bf16)(vt[j] - (float)ht);
                }
            }
            accH[ct] = __builtin_amdgcn_mfma_f32_16x16x32_bf16(a_hi, bh_hi, accH[ct], 0, 0, 0);
            accT[ct] = __builtin_amdgcn_mfma_f32_16x16x32_bf16(a_hi, bt_hi, accT[ct], 0, 0, 0);
            if (!isbf) {   // wave-uniform branch
                accH[ct] = __builtin_amdgcn_mfma_f32_16x16x32_bf16(a_lo, bh_hi, accH[ct], 0, 0, 0);
                accH[ct] = __builtin_amdgcn_mfma_f32_16x16x32_bf16(a_hi, bh_lo, accH[ct], 0, 0, 0);
                accT[ct] = __builtin_amdgcn_mfma_f32_16x16x32_bf16(a_lo, bt_hi, accT[ct], 0, 0, 0);
                accT[ct] = __builtin_amdgcn_mfma_f32_16x16x32_bf16(a_hi, bt_lo, accT[ct], 0, 0, 0);
            }
        }
    }
    // C/D layout: col = lane&15, row = quad*4 + reg   [m89-verified]
    for (int ct = 0; ct < 8; ++ct) {
        int col = ct * 16 + l16;
        for (int r2 = 0; r2 < 4; ++r2) {
            int orow = rowBase + quad * 4 + r2;
            if (orow < NN) {
                xh[(size_t)orow * KRH + col] = __float2bfloat16(accH[ct][r2]);
                xt[(size_t)orow * KRH + col] = __float2bfloat16(accT[ct][r2]);
            }
        }
    }
}

// One wave per node: 8 dot products of length 128.
__global__ __launch_bounds__(256) void k_scores(const __hip_bfloat16* __restrict__ xh,
                                                const __hip_bfloat16* __restrict__ xt,
                                                const float* __restrict__ ah, const float* __restrict__ at,
                                                float4* __restrict__ sp, float4* __restrict__ dp) {
    int lane = threadIdx.x & 63;
    int w = threadIdx.x >> 6;
    int n = blockIdx.x * 4 + w;
    if (n >= NN) return;
    float xh0 = __bfloat162float(xh[(size_t)n*KRH + lane]);
    float xh1 = __bfloat162float(xh[(size_t)n*KRH + 64 + lane]);
    float xt0 = __bfloat162float(xt[(size_t)n*KRH + lane]);
    float xt1 = __bfloat162float(xt[(size_t)n*KRH + 64 + lane]);
    float ah00 = ah[lane],       ah01 = ah[64 + lane];
    float ah10 = ah[128 + lane], ah11 = ah[192 + lane];
    float at00 = at[lane],       at01 = at[64 + lane];
    float at10 = at[128 + lane], at11 = at[192 + lane];
    float v[8];
    v[0] = xh0*ah00 + xh1*ah01;  // s_hh h0
    v[1] = xh0*ah10 + xh1*ah11;  // s_hh h1
    v[2] = xt0*ah00 + xt1*ah01;  // s_th h0
    v[3] = xt0*ah10 + xt1*ah11;  // s_th h1
    v[4] = xt0*at00 + xt1*at01;  // s_tt h0
    v[5] = xt0*at10 + xt1*at11;  // s_tt h1
    v[6] = xh0*at00 + xh1*at01;  // s_ht h0
    v[7] = xh0*at10 + xh1*at11;  // s_ht h1
    for (int off = 32; off; off >>= 1)
        for (int j = 0; j < 8; ++j) v[j] += __shfl_xor(v[j], off);
    if (lane == 0) {
        sp[n] = make_float4(v[0], v[1], v[2], v[3]);
        dp[n] = make_float4(v[4], v[5], v[6], v[7]);
    }
}

__device__ __forceinline__ float eexp(float x) {
    x = x > 0.f ? x : 0.01f * x;       // leaky_relu(0.01)
    x = fminf(x, 50.f);                // overflow guard
    return __expf(x);
}

// Per edge: 4 exp scores -> LDS-staged segment sums + per-rel histogram.
__global__ __launch_bounds__(256) void k_edge(const int* __restrict__ src, const int* __restrict__ dst,
                                              const int* __restrict__ rel,
                                              const float4* __restrict__ sp, const float4* __restrict__ dp,
                                              float* __restrict__ sums, unsigned* __restrict__ counts) {
    __shared__ float ls[NR * 4];
    __shared__ unsigned lc[NR];
    for (int i = threadIdx.x; i < NR * 4; i += 256) ls[i] = 0.f;
    for (int i = threadIdx.x; i < NR; i += 256) lc[i] = 0u;
    __syncthreads();
    int stride = gridDim.x * blockDim.x;
    for (int e = blockIdx.x * blockDim.x + threadIdx.x; e < NE; e += stride) {
        int s = clampi(src[e], NN), d = clampi(dst[e], NN), r = clampi(rel[e], NR);
        float4 a = sp[s], b = dp[d];
        atomicAdd(&ls[r*4+0], eexp(a.x + b.x));
        atomicAdd(&ls[r*4+1], eexp(a.y + b.y));
        atomicAdd(&ls[r*4+2], eexp(a.z + b.z));
        atomicAdd(&ls[r*4+3], eexp(a.w + b.w));
        atomicAdd(&lc[r], 1u);
    }
    __syncthreads();
    for (int i = threadIdx.x; i < NR * 4; i += 256)
        if (ls[i] != 0.f) atomicAdd(&sums[i], ls[i]);
    for (int i = threadIdx.x; i < NR; i += 256)
        if (lc[i]) atomicAdd(&counts[i], lc[i]);
}

// Single-block exclusive scan of counts[500] -> base, cursor.
__global__ __launch_bounds__(512) void k_scan(const unsigned* __restrict__ counts,
                                              unsigned* __restrict__ base, unsigned* __restrict__ cursor) {
    __shared__ unsigned sc[512];
    int t = threadIdx.x;
    sc[t] = (t < NR) ? counts[t] : 0u;
    __syncthreads();
    for (int off = 1; off < 512; off <<= 1) {
        unsigned add = (t >= off) ? sc[t - off] : 0u;
        __syncthreads();
        sc[t] += add;
        __syncthreads();
    }
    if (t < NR) {
        unsigned b = (t == 0) ? 0u : sc[t - 1];
        base[t] = b;
        cursor[t] = b;
    }
    if (t == NR) base[NR] = sc[NR - 1];
}

// LDS-staged counting-sort scatter: 64 blocks x 12500 edges. Per block:
// local histogram -> ONE global atomic per (block,rel) range-reservation ->
// scatter through LDS cursors. Global atomics: 800K -> 32K.
#define SB 64
__global__ __launch_bounds__(256) void k_scatter(const int* __restrict__ rel,
                                                 unsigned* __restrict__ cursor, unsigned* __restrict__ elist) {
    __shared__ unsigned lh[NR];
    __shared__ unsigned lcur[NR];
    int t = threadIdx.x;
    unsigned lo = blockIdx.x * (NE / SB);
    unsigned hi = lo + (NE / SB);
    for (int i = t; i < NR; i += 256) lh[i] = 0u;
    __syncthreads();
    for (unsigned e = lo + t; e < hi; e += 256)
        atomicAdd(&lh[clampi(rel[e], NR)], 1u);
    __syncthreads();
    for (int i = t; i < NR; i += 256)
        lcur[i] = lh[i] ? atomicAdd(&cursor[i], lh[i]) : 0u;
    __syncthreads();
    for (unsigned e = lo + t; e < hi; e += 256) {
        int r = clampi(rel[e], NR);
        unsigned pos = atomicAdd(&lcur[r], 1u);
        if (pos < NE) elist[pos] = e;
    }
}

// 8 blocks/rel x 256 thr. Two-phase per 256-edge chunk:
//  A: each thread resolves ONE edge (indices + softmax weights) into LDS —
//     the gather-latency chain is paid breadth-wise, not serially.
//  B: 4 waves split staged edges 4-way; lane reads bf16x2 (4B) of the x_r
//     row; addresses come from LDS so loads pipeline freely.
#define PB2 8
__global__ __launch_bounds__(256) void k_acc(const int* __restrict__ src, const int* __restrict__ dst,
                                             const float4* __restrict__ sp, const float4* __restrict__ dp,
                                             const float4* __restrict__ sums4,
                                             const unsigned* __restrict__ counts, const unsigned* __restrict__ base,
                                             const unsigned* __restrict__ elist,
                                             const __hip_bfloat16* __restrict__ xh,
                                             const __hip_bfloat16* __restrict__ xt,
                                             float* __restrict__ acc) {
    __shared__ unsigned lsn[256], ldn[256];
    __shared__ float lw1[256], lw2[256];
    __shared__ float red[4][128];
    int r = blockIdx.x / PB2;
    int p = blockIdx.x % PB2;
    int t = threadIdx.x, lane = t & 63, wv = t >> 6;
    int c2 = lane * 2;
    unsigned cnt = counts[r];
    if (cnt > NE) cnt = 0;            // poison guard
    unsigned b0 = base[r];
    float4 s = sums4[r];
    float inv0 = 1.f/(s.x + 1e-16f), inv1 = 1.f/(s.y + 1e-16f);
    float inv2 = 1.f/(s.z + 1e-16f), inv3 = 1.f/(s.w + 1e-16f);
    float ax = 0.f, ay = 0.f;

    for (unsigned cb = (unsigned)p * 256u; cb < cnt; cb += PB2 * 256u) {
        unsigned cn = cnt - cb; if (cn > 256u) cn = 256u;
        __syncthreads();                      // previous chunk's readers done
        if ((unsigned)t < cn) {
            unsigned e = elist[b0 + cb + t];
            int sn = clampi(src[e], NN), dn = clampi(dst[e], NN);
            float4 av = sp[sn], bv = dp[dn];
            lsn[t] = (unsigned)sn; ldn[t] = (unsigned)dn;
            lw1[t] = eexp(av.x + bv.x) * inv0 + eexp(av.y + bv.y) * inv1;
            lw2[t] = eexp(av.z + bv.z) * inv2 + eexp(av.w + bv.w) * inv3;
        }
        __syncthreads();
        for (unsigned j = (unsigned)wv; j < cn; j += 4) {
            unsigned sn = lsn[j], dn = ldn[j];
            float w1 = lw1[j], w2 = lw2[j];
            unsigned uh = *(const unsigned*)((const unsigned short*)xh + (size_t)sn * KRH + c2);
            unsigned ut = *(const unsigned*)((const unsigned short*)xt + (size_t)dn * KRH + c2);
            float hx = __uint_as_float(uh << 16);
            float hy = __uint_as_float(uh & 0xffff0000u);
            float tx = __uint_as_float(ut << 16);
            float ty = __uint_as_float(ut & 0xffff0000u);
            ax = fmaf(w1, hx, fmaf(w2, tx, ax));
            ay = fmaf(w1, hy, fmaf(w2, ty, ay));
        }
    }
    __syncthreads();
    red[wv][c2] = ax; red[wv][c2 + 1] = ay;
    __syncthreads();
    if (wv == 0) {
        float vx = red[0][c2] + red[1][c2] + red[2][c2] + red[3][c2];
        float vy = red[0][c2+1] + red[1][c2+1] + red[2][c2+1] + red[3][c2+1];
        atomicAdd(&acc[(size_t)r * KRH + c2], vx);
        atomicAdd(&acc[(size_t)r * KRH + c2 + 1], vy);
    }
}

// Output dtype follows input dtype (reference returns x_e.dtype).
__global__ __launch_bounds__(256) void k_out(const float* __restrict__ acc,
                                             const unsigned* __restrict__ flag, void* __restrict__ out) {
    int i = blockIdx.x * 256 + threadIdx.x;
    if (i < NR * KRH) {
        float v = acc[i] * 0.25f;     // / num_heads(2) / 2
        if (!isfinite(v)) v = 0.f;    // diagnostic backstop
        if (flag[0]) ((__hip_bfloat16*)out)[i] = __float2bfloat16(v);
        else         ((float*)out)[i] = v;
    }
}

extern "C" void kernel_launch(void* const* d_in, const int* in_sizes, int n_in,
                              void* d_out, int out_size, void* d_ws, size_t ws_size,
                              hipStream_t stream) {
    const void* xe  = d_in[0];
    const int* eidx = (const int*)d_in[1];
    const int* rel  = (const int*)d_in[2];
    const void* wh  = d_in[3];
    const void* wt  = d_in[4];
    const void* ahp = d_in[5];
    const void* atp = d_in[6];

    const int* src = eidx;
    const int* dst = eidx + NE;

    char* ws = (char*)d_ws;
    __hip_bfloat16* xh = (__hip_bfloat16*)(ws + OFF_XH);
    __hip_bfloat16* xt = (__hip_bfloat16*)(ws + OFF_XT);
    float4*   sp     = (float4*)(ws + OFF_SP);
    float4*   dp     = (float4*)(ws + OFF_DP);
    float*    sums   = (float*)(ws + OFF_SUMS);
    unsigned* counts = (unsigned*)(ws + OFF_CNT);
    unsigned* basep  = (unsigned*)(ws + OFF_BASE);
    unsigned* cursor = (unsigned*)(ws + OFF_CUR);
    unsigned* elist  = (unsigned*)(ws + OFF_ELIST);
    float*    acc    = (float*)(ws + OFF_ACC);
    float*    ah32   = (float*)(ws + OFF_AH);
    float*    at32   = (float*)(ws + OFF_AT);
    unsigned* flag   = (unsigned*)(ws + OFF_FLAG);

    k_init<<<261, 256, 0, stream>>>((const unsigned*)xe, ahp, atp, flag, ah32, at32,
                                     (unsigned*)(ws + OFF_SUMS), (unsigned*)acc);
    k_gemm<<<(NN + 63) / 64, 256, 0, stream>>>(xe, wh, wt, flag, xh, xt);
    k_scores<<<(NN + 3) / 4, 256, 0, stream>>>(xh, xt, ah32, at32, sp, dp);
    k_edge<<<512, 256, 0, stream>>>(src, dst, rel, sp, dp, sums, counts);
    k_scan<<<1, 512, 0, stream>>>(counts, basep, cursor);
    k_scatter<<<SB, 256, 0, stream>>>(rel, cursor, elist);
    k_acc<<<NR * PB2, 256, 0, stream>>>(src, dst, sp, dp, (const float4*)sums, counts, basep, elist, xh, xt, acc);
    k_out<<<(NR * KRH + 255) / 256, 256, 0, stream>>>(acc, flag, d_out);
}

// Round 6
// 400.486 us; speedup vs baseline: 1.8930x; 1.0358x over previous
//
#include <hip/hip_runtime.h>
#include <hip/hip_bf16.h>

#define NN 50000      // nodes
#define NE 800000     // edges
#define NR 500        // relations
#define KEH 256       // input feat dim
#define KRH 128       // proj feat dim

typedef __attribute__((ext_vector_type(8))) __bf16 bf16x8;
typedef __attribute__((ext_vector_type(4))) float f32x4;

// ---- workspace layout (bytes, 16B aligned), total ~29.5 MiB ----
#define OFF_XH     0UL            // [NN][128] bf16  12,800,000
#define OFF_XT     12800000UL     // [NN][128] bf16  12,800,000
#define OFF_SP     25600000UL     // [NN] float4 (s_hh0,s_hh1,s_th0,s_th1)
#define OFF_DP     26400000UL     // [NN] float4 (s_tt0,s_tt1,s_ht0,s_ht1)
#define OFF_SUMS   27200000UL     // [NR] float4 softmax denominators (8000 B)
#define OFF_CNT    27208000UL     // [NR] u32 counts (contiguous after sums)
#define OFF_BASE   27210048UL     // [NR+1] u32 segment bases
#define OFF_CUR    27212096UL     // [NR] u32 scatter cursors
#define OFF_ELIST  27214144UL     // [NE] u32 edge ids bucketed by rel
#define OFF_ACC    30414144UL     // [NR][128] f32 accumulator
#define OFF_AH     30670144UL     // [256] f32 a_h
#define OFF_AT     30671168UL     // [256] f32 a_t
#define OFF_FLAG   30672192UL     // u32: 1 = inputs are bf16, 0 = f32
#define OFF_WHH    30672256UL     // [128][256] bf16 w_h hi
#define OFF_WHL    30737792UL     // [128][256] bf16 w_h lo
#define OFF_WTH    30803328UL     // [128][256] bf16 w_t hi
#define OFF_WTL    30868864UL     // [128][256] bf16 w_t lo

__device__ __forceinline__ int clampi(int v, int hi) {  // [0, hi)
    v = v < 0 ? 0 : v;
    return v >= hi ? hi - 1 : v;
}

// block0: sniff input dtype from x_e bit patterns + convert a_h/a_t to f32.
// blocks 1..: zero sums+counts (2500 u32) and acc (64000 u32).
__global__ __launch_bounds__(256) void k_init(const unsigned* __restrict__ xe_raw,
                                              const void* __restrict__ ah_in, const void* __restrict__ at_in,
                                              unsigned* __restrict__ flag, float* __restrict__ ah32,
                                              float* __restrict__ at32,
                                              unsigned* __restrict__ sums_cnt, unsigned* __restrict__ accz) {
    if (blockIdx.x == 0) {
        __shared__ int votes;
        int t = threadIdx.x;
        if (t == 0) votes = 0;
        __syncthreads();
        if (t < 64) {
            // low u16 of each 32-bit word: uniform mantissa bits if x_e is f32
            // (~6% hit rate below); an N(0,1) bf16 value (exp ~127) if bf16.
            unsigned w = xe_raw[t];
            unsigned ex = (w >> 7) & 0xFFu;
            if (ex >= 115u && ex <= 131u) atomicAdd(&votes, 1);
        }
        __syncthreads();
        int isbf = votes >= 32;
        if (t == 0) flag[0] = (unsigned)isbf;
        if (t < 256) {
            ah32[t] = isbf ? __bfloat162float(((const __hip_bfloat16*)ah_in)[t]) : ((const float*)ah_in)[t];
            at32[t] = isbf ? __bfloat162float(((const __hip_bfloat16*)at_in)[t]) : ((const float*)at_in)[t];
        }
    } else {
        int stride = (gridDim.x - 1) * 256;
        int t0 = (blockIdx.x - 1) * 256 + threadIdx.x;
        for (int i = t0; i < 2500; i += stride) sums_cnt[i] = 0u;
        for (int i = t0; i < NR * KRH; i += stride) accz[i] = 0u;
    }
}

// One-time split of w_h/w_t into bf16 hi/lo (f32 mode) or copy+zero (bf16 mode).
// Removes 782x redundant per-block VALU conversion from k_gemm's inner loop.
__global__ __launch_bounds__(256) void k_split(const void* __restrict__ wh, const void* __restrict__ wt,
                                               const unsigned* __restrict__ flag,
                                               __bf16* __restrict__ whh, __bf16* __restrict__ whl,
                                               __bf16* __restrict__ wth, __bf16* __restrict__ wtl) {
    int i = blockIdx.x * 256 + threadIdx.x;
    if (i >= KRH * KEH) return;
    if (flag[0]) {
        whh[i] = ((const __bf16*)wh)[i]; whl[i] = (__bf16)0.f;
        wth[i] = ((const __bf16*)wt)[i]; wtl[i] = (__bf16)0.f;
    } else {
        float a = ((const float*)wh)[i];
        float b = ((const float*)wt)[i];
        __bf16 ah_ = (__bf16)a, bh_ = (__bf16)b;
        whh[i] = ah_; whl[i] = (__bf16)(a - (float)ah_);
        wth[i] = bh_; wtl[i] = (__bf16)(b - (float)bh_);
    }
}

// C[m,n] = sum_k A[m,k] * W[n,k]; A = x_e (f32 or bf16), B pre-split bf16 hi/lo.
// f32 mode: 3-pass split-bf16 (hi*hi + lo*hi + hi*lo) -> ~f32 accuracy.
__global__ __launch_bounds__(256) void k_gemm(const void* __restrict__ xe,
                                              const unsigned* __restrict__ flag,
                                              const __bf16* __restrict__ whh, const __bf16* __restrict__ whl,
                                              const __bf16* __restrict__ wth, const __bf16* __restrict__ wtl,
                                              __hip_bfloat16* __restrict__ xh, __hip_bfloat16* __restrict__ xt) {
    const int isbf = (int)flag[0];
    int wave = threadIdx.x >> 6;
    int lane = threadIdx.x & 63;
    int quad = lane >> 4;
    int l16  = lane & 15;
    int rowBase = blockIdx.x * 64 + wave * 16;
    int arow = rowBase + l16;
    if (arow >= NN) arow = NN - 1;   // clamp; OOB rows never stored

    f32x4 accH[8], accT[8];
    for (int t = 0; t < 8; ++t) { accH[t] = (f32x4){0.f,0.f,0.f,0.f}; accT[t] = (f32x4){0.f,0.f,0.f,0.f}; }

    for (int ks = 0; ks < 8; ++ks) {
        int kb = ks * 32 + quad * 8;
        bf16x8 a_hi, a_lo;
        if (isbf) {
            a_hi = *(const bf16x8*)((const __bf16*)xe + (size_t)arow * KEH + kb);
        } else {
            const float* p = (const float*)xe + (size_t)arow * KEH + kb;
            float4 v0 = *(const float4*)p, v1 = *(const float4*)(p + 4);
            float v[8] = {v0.x, v0.y, v0.z, v0.w, v1.x, v1.y, v1.z, v1.w};
            for (int j = 0; j < 8; ++j) {
                __bf16 h = (__bf16)v[j];
                a_hi[j] = h;
                a_lo[j] = (__bf16)(v[j] - (float)h);
            }
        }
        for (int ct = 0; ct < 8; ++ct) {
            size_t widx = (size_t)(ct * 16 + l16) * KEH + kb;
            bf16x8 bh_hi = *(const bf16x8*)(whh + widx);
            bf16x8 bt_hi = *(const bf16x8*)(wth + widx);
            accH[ct] = __builtin_amdgcn_mfma_f32_16x16x32_bf16(a_hi, bh_hi, accH[ct], 0, 0, 0);
            accT[ct] = __builtin_amdgcn_mfma_f32_16x16x32_bf16(a_hi, bt_hi, accT[ct], 0, 0, 0);
            if (!isbf) {   // wave-uniform branch
                bf16x8 bh_lo = *(const bf16x8*)(whl + widx);
                bf16x8 bt_lo = *(const bf16x8*)(wtl + widx);
                accH[ct] = __builtin_amdgcn_mfma_f32_16x16x32_bf16(a_lo, bh_hi, accH[ct], 0, 0, 0);
                accH[ct] = __builtin_amdgcn_mfma_f32_16x16x32_bf16(a_hi, bh_lo, accH[ct], 0, 0, 0);
                accT[ct] = __builtin_amdgcn_mfma_f32_16x16x32_bf16(a_lo, bt_hi, accT[ct], 0, 0, 0);
                accT[ct] = __builtin_amdgcn_mfma_f32_16x16x32_bf16(a_hi, bt_lo, accT[ct], 0, 0, 0);
            }
        }
    }
    // C/D layout: col = lane&15, row = quad*4 + reg   [m89-verified]
    for (int ct = 0; ct < 8; ++ct) {
        int col = ct * 16 + l16;
        for (int r2 = 0; r2 < 4; ++r2) {
            int orow = rowBase + quad * 4 + r2;
            if (orow < NN) {
                xh[(size_t)orow * KRH + col] = __float2bfloat16(accH[ct][r2]);
                xt[(size_t)orow * KRH + col] = __float2bfloat16(accT[ct][r2]);
            }
        }
    }
}

// One wave per node: 8 dot products of length 128.
__global__ __launch_bounds__(256) void k_scores(const __hip_bfloat16* __restrict__ xh,
                                                const __hip_bfloat16* __restrict__ xt,
                                                const float* __restrict__ ah, const float* __restrict__ at,
                                                float4* __restrict__ sp, float4* __restrict__ dp) {
    int lane = threadIdx.x & 63;
    int w = threadIdx.x >> 6;
    int n = blockIdx.x * 4 + w;
    if (n >= NN) return;
    float xh0 = __bfloat162float(xh[(size_t)n*KRH + lane]);
    float xh1 = __bfloat162float(xh[(size_t)n*KRH + 64 + lane]);
    float xt0 = __bfloat162float(xt[(size_t)n*KRH + lane]);
    float xt1 = __bfloat162float(xt[(size_t)n*KRH + 64 + lane]);
    float ah00 = ah[lane],       ah01 = ah[64 + lane];
    float ah10 = ah[128 + lane], ah11 = ah[192 + lane];
    float at00 = at[lane],       at01 = at[64 + lane];
    float at10 = at[128 + lane], at11 = at[192 + lane];
    float v[8];
    v[0] = xh0*ah00 + xh1*ah01;  // s_hh h0
    v[1] = xh0*ah10 + xh1*ah11;  // s_hh h1
    v[2] = xt0*ah00 + xt1*ah01;  // s_th h0
    v[3] = xt0*ah10 + xt1*ah11;  // s_th h1
    v[4] = xt0*at00 + xt1*at01;  // s_tt h0
    v[5] = xt0*at10 + xt1*at11;  // s_tt h1
    v[6] = xh0*at00 + xh1*at01;  // s_ht h0
    v[7] = xh0*at10 + xh1*at11;  // s_ht h1
    for (int off = 32; off; off >>= 1)
        for (int j = 0; j < 8; ++j) v[j] += __shfl_xor(v[j], off);
    if (lane == 0) {
        sp[n] = make_float4(v[0], v[1], v[2], v[3]);
        dp[n] = make_float4(v[4], v[5], v[6], v[7]);
    }
}

__device__ __forceinline__ float eexp(float x) {
    x = x > 0.f ? x : 0.01f * x;       // leaky_relu(0.01)
    x = fminf(x, 50.f);                // overflow guard
    return __expf(x);
}

// Per edge: 4 exp scores -> LDS-staged segment sums + per-rel histogram.
__global__ __launch_bounds__(256) void k_edge(const int* __restrict__ src, const int* __restrict__ dst,
                                              const int* __restrict__ rel,
                                              const float4* __restrict__ sp, const float4* __restrict__ dp,
                                              float* __restrict__ sums, unsigned* __restrict__ counts) {
    __shared__ float ls[NR * 4];
    __shared__ unsigned lc[NR];
    for (int i = threadIdx.x; i < NR * 4; i += 256) ls[i] = 0.f;
    for (int i = threadIdx.x; i < NR; i += 256) lc[i] = 0u;
    __syncthreads();
    int stride = gridDim.x * blockDim.x;
    for (int e = blockIdx.x * blockDim.x + threadIdx.x; e < NE; e += stride) {
        int s = clampi(src[e], NN), d = clampi(dst[e], NN), r = clampi(rel[e], NR);
        float4 a = sp[s], b = dp[d];
        atomicAdd(&ls[r*4+0], eexp(a.x + b.x));
        atomicAdd(&ls[r*4+1], eexp(a.y + b.y));
        atomicAdd(&ls[r*4+2], eexp(a.z + b.z));
        atomicAdd(&ls[r*4+3], eexp(a.w + b.w));
        atomicAdd(&lc[r], 1u);
    }
    __syncthreads();
    for (int i = threadIdx.x; i < NR * 4; i += 256)
        if (ls[i] != 0.f) atomicAdd(&sums[i], ls[i]);
    for (int i = threadIdx.x; i < NR; i += 256)
        if (lc[i]) atomicAdd(&counts[i], lc[i]);
}

// Single-block exclusive scan of counts[500] -> base, cursor.
__global__ __launch_bounds__(512) void k_scan(const unsigned* __restrict__ counts,
                                              unsigned* __restrict__ base, unsigned* __restrict__ cursor) {
    __shared__ unsigned sc[512];
    int t = threadIdx.x;
    sc[t] = (t < NR) ? counts[t] : 0u;
    __syncthreads();
    for (int off = 1; off < 512; off <<= 1) {
        unsigned add = (t >= off) ? sc[t - off] : 0u;
        __syncthreads();
        sc[t] += add;
        __syncthreads();
    }
    if (t < NR) {
        unsigned b = (t == 0) ? 0u : sc[t - 1];
        base[t] = b;
        cursor[t] = b;
    }
    if (t == NR) base[NR] = sc[NR - 1];
}

// LDS-staged counting-sort scatter: 64 blocks x 12500 edges. Per block:
// local histogram -> ONE global atomic per (block,rel) range-reservation ->
// scatter through LDS cursors. Global atomics: 800K -> 32K.
#define SB 64
__global__ __launch_bounds__(256) void k_scatter(const int* __restrict__ rel,
                                                 unsigned* __restrict__ cursor, unsigned* __restrict__ elist) {
    __shared__ unsigned lh[NR];
    __shared__ unsigned lcur[NR];
    int t = threadIdx.x;
    unsigned lo = blockIdx.x * (NE / SB);
    unsigned hi = lo + (NE / SB);
    for (int i = t; i < NR; i += 256) lh[i] = 0u;
    __syncthreads();
    for (unsigned e = lo + t; e < hi; e += 256)
        atomicAdd(&lh[clampi(rel[e], NR)], 1u);
    __syncthreads();
    for (int i = t; i < NR; i += 256)
        lcur[i] = lh[i] ? atomicAdd(&cursor[i], lh[i]) : 0u;
    __syncthreads();
    for (unsigned e = lo + t; e < hi; e += 256) {
        int r = clampi(rel[e], NR);
        unsigned pos = atomicAdd(&lcur[r], 1u);
        if (pos < NE) elist[pos] = e;
    }
}

// 8 blocks/rel x 256 thr. Two-phase per 256-edge chunk:
//  A: each thread resolves ONE edge (indices + softmax weights) into LDS —
//     the gather-latency chain is paid breadth-wise, not serially.
//  B: 4 waves split staged edges 4-way; lane reads bf16x2 (4B) of the x_r
//     row; addresses come from LDS so loads pipeline freely.
#define PB2 8
__global__ __launch_bounds__(256) void k_acc(const int* __restrict__ src, const int* __restrict__ dst,
                                             const float4* __restrict__ sp, const float4* __restrict__ dp,
                                             const float4* __restrict__ sums4,
                                             const unsigned* __restrict__ counts, const unsigned* __restrict__ base,
                                             const unsigned* __restrict__ elist,
                                             const __hip_bfloat16* __restrict__ xh,
                                             const __hip_bfloat16* __restrict__ xt,
                                             float* __restrict__ acc) {
    __shared__ unsigned lsn[256], ldn[256];
    __shared__ float lw1[256], lw2[256];
    __shared__ float red[4][128];
    int r = blockIdx.x / PB2;
    int p = blockIdx.x % PB2;
    int t = threadIdx.x, lane = t & 63, wv = t >> 6;
    int c2 = lane * 2;
    unsigned cnt = counts[r];
    if (cnt > NE) cnt = 0;            // poison guard
    unsigned b0 = base[r];
    float4 s = sums4[r];
    float inv0 = 1.f/(s.x + 1e-16f), inv1 = 1.f/(s.y + 1e-16f);
    float inv2 = 1.f/(s.z + 1e-16f), inv3 = 1.f/(s.w + 1e-16f);
    float ax = 0.f, ay = 0.f;

    for (unsigned cb = (unsigned)p * 256u; cb < cnt; cb += PB2 * 256u) {
        unsigned cn = cnt - cb; if (cn > 256u) cn = 256u;
        __syncthreads();                      // previous chunk's readers done
        if ((unsigned)t < cn) {
            unsigned e = elist[b0 + cb + t];
            int sn = clampi(src[e], NN), dn = clampi(dst[e], NN);
            float4 av = sp[sn], bv = dp[dn];
            lsn[t] = (unsigned)sn; ldn[t] = (unsigned)dn;
            lw1[t] = eexp(av.x + bv.x) * inv0 + eexp(av.y + bv.y) * inv1;
            lw2[t] = eexp(av.z + bv.z) * inv2 + eexp(av.w + bv.w) * inv3;
        }
        __syncthreads();
        for (unsigned j = (unsigned)wv; j < cn; j += 4) {
            unsigned sn = lsn[j], dn = ldn[j];
            float w1 = lw1[j], w2 = lw2[j];
            unsigned uh = *(const unsigned*)((const unsigned short*)xh + (size_t)sn * KRH + c2);
            unsigned ut = *(const unsigned*)((const unsigned short*)xt + (size_t)dn * KRH + c2);
            float hx = __uint_as_float(uh << 16);
            float hy = __uint_as_float(uh & 0xffff0000u);
            float tx = __uint_as_float(ut << 16);
            float ty = __uint_as_float(ut & 0xffff0000u);
            ax = fmaf(w1, hx, fmaf(w2, tx, ax));
            ay = fmaf(w1, hy, fmaf(w2, ty, ay));
        }
    }
    __syncthreads();
    red[wv][c2] = ax; red[wv][c2 + 1] = ay;
    __syncthreads();
    if (wv == 0) {
        float vx = red[0][c2] + red[1][c2] + red[2][c2] + red[3][c2];
        float vy = red[0][c2+1] + red[1][c2+1] + red[2][c2+1] + red[3][c2+1];
        atomicAdd(&acc[(size_t)r * KRH + c2], vx);
        atomicAdd(&acc[(size_t)r * KRH + c2 + 1], vy);
    }
}

// Output dtype follows input dtype (reference returns x_e.dtype).
__global__ __launch_bounds__(256) void k_out(const float* __restrict__ acc,
                                             const unsigned* __restrict__ flag, void* __restrict__ out) {
    int i = blockIdx.x * 256 + threadIdx.x;
    if (i < NR * KRH) {
        float v = acc[i] * 0.25f;     // / num_heads(2) / 2
        if (!isfinite(v)) v = 0.f;    // diagnostic backstop
        if (flag[0]) ((__hip_bfloat16*)out)[i] = __float2bfloat16(v);
        else         ((float*)out)[i] = v;
    }
}

extern "C" void kernel_launch(void* const* d_in, const int* in_sizes, int n_in,
                              void* d_out, int out_size, void* d_ws, size_t ws_size,
                              hipStream_t stream) {
    const void* xe  = d_in[0];
    const int* eidx = (const int*)d_in[1];
    const int* rel  = (const int*)d_in[2];
    const void* wh  = d_in[3];
    const void* wt  = d_in[4];
    const void* ahp = d_in[5];
    const void* atp = d_in[6];

    const int* src = eidx;
    const int* dst = eidx + NE;

    char* ws = (char*)d_ws;
    __hip_bfloat16* xh = (__hip_bfloat16*)(ws + OFF_XH);
    __hip_bfloat16* xt = (__hip_bfloat16*)(ws + OFF_XT);
    float4*   sp     = (float4*)(ws + OFF_SP);
    float4*   dp     = (float4*)(ws + OFF_DP);
    float*    sums   = (float*)(ws + OFF_SUMS);
    unsigned* counts = (unsigned*)(ws + OFF_CNT);
    unsigned* basep  = (unsigned*)(ws + OFF_BASE);
    unsigned* cursor = (unsigned*)(ws + OFF_CUR);
    unsigned* elist  = (unsigned*)(ws + OFF_ELIST);
    float*    acc    = (float*)(ws + OFF_ACC);
    float*    ah32   = (float*)(ws + OFF_AH);
    float*    at32   = (float*)(ws + OFF_AT);
    unsigned* flag   = (unsigned*)(ws + OFF_FLAG);
    __bf16*   whh    = (__bf16*)(ws + OFF_WHH);
    __bf16*   whl    = (__bf16*)(ws + OFF_WHL);
    __bf16*   wth    = (__bf16*)(ws + OFF_WTH);
    __bf16*   wtl    = (__bf16*)(ws + OFF_WTL);

    k_init<<<261, 256, 0, stream>>>((const unsigned*)xe, ahp, atp, flag, ah32, at32,
                                     (unsigned*)(ws + OFF_SUMS), (unsigned*)acc);
    k_split<<<(KRH * KEH + 255) / 256, 256, 0, stream>>>(wh, wt, flag, whh, whl, wth, wtl);
    k_gemm<<<(NN + 63) / 64, 256, 0, stream>>>(xe, flag, whh, whl, wth, wtl, xh, xt);
    k_scores<<<(NN + 3) / 4, 256, 0, stream>>>(xh, xt, ah32, at32, sp, dp);
    k_edge<<<512, 256, 0, stream>>>(src, dst, rel, sp, dp, sums, counts);
    k_scan<<<1, 512, 0, stream>>>(counts, basep, cursor);
    k_scatter<<<SB, 256, 0, stream>>>(rel, cursor, elist);
    k_acc<<<NR * PB2, 256, 0, stream>>>(src, dst, sp, dp, (const float4*)sums, counts, basep, elist, xh, xt, acc);
    k_out<<<(NR * KRH + 255) / 256, 256, 0, stream>>>(acc, flag, d_out);
}

// Round 7
// 310.232 us; speedup vs baseline: 2.4437x; 1.2909x over previous
//
#include <hip/hip_runtime.h>
#include <hip/hip_bf16.h>

#define NN 50000      // nodes
#define NE 800000     // edges
#define NR 500        // relations
#define KEH 256       // input feat dim
#define KRH 128       // proj feat dim

typedef __attribute__((ext_vector_type(8))) __bf16 bf16x8;
typedef __attribute__((ext_vector_type(4))) float f32x4;

// ---- workspace layout (bytes, 16B aligned), total ~29.5 MiB ----
#define OFF_XH     0UL            // [NN][128] bf16  12,800,000
#define OFF_XT     12800000UL     // [NN][128] bf16  12,800,000
#define OFF_SP     25600000UL     // [NN] float4 (s_hh0,s_hh1,s_th0,s_th1)
#define OFF_DP     26400000UL     // [NN] float4 (s_tt0,s_tt1,s_ht0,s_ht1)
#define OFF_SUMS   27200000UL     // [NR] float4 softmax denominators (8000 B)
#define OFF_CNT    27208000UL     // [NR] u32 counts (contiguous after sums)
#define OFF_BASE   27210048UL     // [NR+1] u32 segment bases
#define OFF_CUR    27212096UL     // [NR] u32 scatter cursors
#define OFF_ELIST  27214144UL     // [NE] u32 edge ids bucketed by rel
#define OFF_ACC    30414144UL     // [NR][128] f32 accumulator
#define OFF_AH     30670144UL     // [256] f32 a_h
#define OFF_AT     30671168UL     // [256] f32 a_t
#define OFF_FLAG   30672192UL     // u32: 1 = inputs are bf16, 0 = f32
#define OFF_WHH    30672256UL     // [128][256] bf16 w_h hi
#define OFF_WHL    30737792UL     // [128][256] bf16 w_h lo
#define OFF_WTH    30803328UL     // [128][256] bf16 w_t hi
#define OFF_WTL    30868864UL     // [128][256] bf16 w_t lo

__device__ __forceinline__ int clampi(int v, int hi) {  // [0, hi)
    v = v < 0 ? 0 : v;
    return v >= hi ? hi - 1 : v;
}

// block0: sniff input dtype from x_e bit patterns + convert a_h/a_t to f32.
// blocks 1..: zero sums+counts (2500 u32) and acc (64000 u32).
__global__ __launch_bounds__(256) void k_init(const unsigned* __restrict__ xe_raw,
                                              const void* __restrict__ ah_in, const void* __restrict__ at_in,
                                              unsigned* __restrict__ flag, float* __restrict__ ah32,
                                              float* __restrict__ at32,
                                              unsigned* __restrict__ sums_cnt, unsigned* __restrict__ accz) {
    if (blockIdx.x == 0) {
        __shared__ int votes;
        int t = threadIdx.x;
        if (t == 0) votes = 0;
        __syncthreads();
        if (t < 64) {
            // low u16 of each 32-bit word: uniform mantissa bits if x_e is f32
            // (~6% hit rate below); an N(0,1) bf16 value (exp ~127) if bf16.
            unsigned w = xe_raw[t];
            unsigned ex = (w >> 7) & 0xFFu;
            if (ex >= 115u && ex <= 131u) atomicAdd(&votes, 1);
        }
        __syncthreads();
        int isbf = votes >= 32;
        if (t == 0) flag[0] = (unsigned)isbf;
        if (t < 256) {
            ah32[t] = isbf ? __bfloat162float(((const __hip_bfloat16*)ah_in)[t]) : ((const float*)ah_in)[t];
            at32[t] = isbf ? __bfloat162float(((const __hip_bfloat16*)at_in)[t]) : ((const float*)at_in)[t];
        }
    } else {
        int stride = (gridDim.x - 1) * 256;
        int t0 = (blockIdx.x - 1) * 256 + threadIdx.x;
        for (int i = t0; i < 2500; i += stride) sums_cnt[i] = 0u;
        for (int i = t0; i < NR * KRH; i += stride) accz[i] = 0u;
    }
}

// One-time split of w_h/w_t into bf16 hi/lo (f32 mode) or copy+zero (bf16 mode).
__global__ __launch_bounds__(256) void k_split(const void* __restrict__ wh, const void* __restrict__ wt,
                                               const unsigned* __restrict__ flag,
                                               __bf16* __restrict__ whh, __bf16* __restrict__ whl,
                                               __bf16* __restrict__ wth, __bf16* __restrict__ wtl) {
    int i = blockIdx.x * 256 + threadIdx.x;
    if (i >= KRH * KEH) return;
    if (flag[0]) {
        whh[i] = ((const __bf16*)wh)[i]; whl[i] = (__bf16)0.f;
        wth[i] = ((const __bf16*)wt)[i]; wtl[i] = (__bf16)0.f;
    } else {
        float a = ((const float*)wh)[i];
        float b = ((const float*)wt)[i];
        __bf16 ah_ = (__bf16)a, bh_ = (__bf16)b;
        whh[i] = ah_; whl[i] = (__bf16)(a - (float)ah_);
        wth[i] = bh_; wtl[i] = (__bf16)(b - (float)bh_);
    }
}

// LDS-staged GEMM: block tile 128 rows x 128 cols, 4 waves x 32 rows.
// Per BK=32 step: cooperatively stage whh/wth(/whl/wtl) slices into LDS
// (row stride 40 = padded, 16B-aligned, conflict-free for b128 reads),
// then fragments via ds_read_b128. f32 mode: 3-pass split-bf16.
#define GM 128
#define WROW 40   // LDS row stride in bf16 elements
__global__ __launch_bounds__(256, 2) void k_gemm(const void* __restrict__ xe,
                                                 const unsigned* __restrict__ flag,
                                                 const __bf16* __restrict__ whh, const __bf16* __restrict__ whl,
                                                 const __bf16* __restrict__ wth, const __bf16* __restrict__ wtl,
                                                 __hip_bfloat16* __restrict__ xh, __hip_bfloat16* __restrict__ xt) {
    const int isbf = (int)flag[0];
    __shared__ __bf16 sw[4][128 * WROW];   // whh, wth, whl, wtl slices (40 KB)
    int t = threadIdx.x;
    int lane = t & 63, wave = t >> 6;
    int quad = lane >> 4, l16 = lane & 15;
    int rowBase = blockIdx.x * GM + wave * 32;
    int r0 = rowBase + l16, r1 = r0 + 16;
    int ar0 = r0 < NN ? r0 : NN - 1;   // clamped A rows; OOB never stored
    int ar1 = r1 < NN ? r1 : NN - 1;

    f32x4 accH0[8], accH1[8], accT0[8], accT1[8];
    for (int i = 0; i < 8; ++i) {
        accH0[i] = (f32x4){0.f,0.f,0.f,0.f}; accH1[i] = (f32x4){0.f,0.f,0.f,0.f};
        accT0[i] = (f32x4){0.f,0.f,0.f,0.f}; accT1[i] = (f32x4){0.f,0.f,0.f,0.f};
    }
    const int nparts = isbf ? 2 : 4;
    const __bf16* wsrc[4] = {whh, wth, whl, wtl};

    for (int ks = 0; ks < 8; ++ks) {
        int kb = ks * 32;
        __syncthreads();                 // previous step's readers done
        for (int part = 0; part < nparts; ++part) {
            const __bf16* wp = wsrc[part];
            for (int half = 0; half < 2; ++half) {
                int idx = half * 256 + t;         // [0,512)
                int row = idx >> 2, ko = (idx & 3) * 8;
                uint4 v = *(const uint4*)(wp + (size_t)row * KEH + kb + ko);
                *(uint4*)(&sw[part][row * WROW + ko]) = v;
            }
        }
        __syncthreads();

        bf16x8 a0h, a0l, a1h, a1l;
        if (isbf) {
            a0h = *(const bf16x8*)((const __bf16*)xe + (size_t)ar0 * KEH + kb + quad * 8);
            a1h = *(const bf16x8*)((const __bf16*)xe + (size_t)ar1 * KEH + kb + quad * 8);
        } else {
            const float* p0 = (const float*)xe + (size_t)ar0 * KEH + kb + quad * 8;
            const float* p1 = (const float*)xe + (size_t)ar1 * KEH + kb + quad * 8;
            float4 u0 = *(const float4*)p0, u1 = *(const float4*)(p0 + 4);
            float4 w0 = *(const float4*)p1, w1 = *(const float4*)(p1 + 4);
            float v0[8] = {u0.x,u0.y,u0.z,u0.w,u1.x,u1.y,u1.z,u1.w};
            float v1[8] = {w0.x,w0.y,w0.z,w0.w,w1.x,w1.y,w1.z,w1.w};
            for (int j = 0; j < 8; ++j) {
                __bf16 h0 = (__bf16)v0[j], h1 = (__bf16)v1[j];
                a0h[j] = h0; a0l[j] = (__bf16)(v0[j] - (float)h0);
                a1h[j] = h1; a1l[j] = (__bf16)(v1[j] - (float)h1);
            }
        }
        for (int ct = 0; ct < 8; ++ct) {
            int fo = (ct * 16 + l16) * WROW + quad * 8;
            bf16x8 fh = *(const bf16x8*)(&sw[0][fo]);
            bf16x8 ft = *(const bf16x8*)(&sw[1][fo]);
            accH0[ct] = __builtin_amdgcn_mfma_f32_16x16x32_bf16(a0h, fh, accH0[ct], 0, 0, 0);
            accH1[ct] = __builtin_amdgcn_mfma_f32_16x16x32_bf16(a1h, fh, accH1[ct], 0, 0, 0);
            accT0[ct] = __builtin_amdgcn_mfma_f32_16x16x32_bf16(a0h, ft, accT0[ct], 0, 0, 0);
            accT1[ct] = __builtin_amdgcn_mfma_f32_16x16x32_bf16(a1h, ft, accT1[ct], 0, 0, 0);
            if (!isbf) {   // wave-uniform
                bf16x8 fhl = *(const bf16x8*)(&sw[2][fo]);
                bf16x8 ftl = *(const bf16x8*)(&sw[3][fo]);
                accH0[ct] = __builtin_amdgcn_mfma_f32_16x16x32_bf16(a0l, fh,  accH0[ct], 0, 0, 0);
                accH0[ct] = __builtin_amdgcn_mfma_f32_16x16x32_bf16(a0h, fhl, accH0[ct], 0, 0, 0);
                accH1[ct] = __builtin_amdgcn_mfma_f32_16x16x32_bf16(a1l, fh,  accH1[ct], 0, 0, 0);
                accH1[ct] = __builtin_amdgcn_mfma_f32_16x16x32_bf16(a1h, fhl, accH1[ct], 0, 0, 0);
                accT0[ct] = __builtin_amdgcn_mfma_f32_16x16x32_bf16(a0l, ft,  accT0[ct], 0, 0, 0);
                accT0[ct] = __builtin_amdgcn_mfma_f32_16x16x32_bf16(a0h, ftl, accT0[ct], 0, 0, 0);
                accT1[ct] = __builtin_amdgcn_mfma_f32_16x16x32_bf16(a1l, ft,  accT1[ct], 0, 0, 0);
                accT1[ct] = __builtin_amdgcn_mfma_f32_16x16x32_bf16(a1h, ftl, accT1[ct], 0, 0, 0);
            }
        }
    }
    // C/D layout: col = lane&15, row = quad*4 + reg   [m89-verified]
    for (int ct = 0; ct < 8; ++ct) {
        int col = ct * 16 + l16;
        for (int r2 = 0; r2 < 4; ++r2) {
            int o0 = rowBase + quad * 4 + r2;
            int o1 = o0 + 16;
            if (o0 < NN) {
                xh[(size_t)o0 * KRH + col] = __float2bfloat16(accH0[ct][r2]);
                xt[(size_t)o0 * KRH + col] = __float2bfloat16(accT0[ct][r2]);
            }
            if (o1 < NN) {
                xh[(size_t)o1 * KRH + col] = __float2bfloat16(accH1[ct][r2]);
                xt[(size_t)o1 * KRH + col] = __float2bfloat16(accT1[ct][r2]);
            }
        }
    }
}

// One wave per node: 8 dot products of length 128.
__global__ __launch_bounds__(256) void k_scores(const __hip_bfloat16* __restrict__ xh,
                                                const __hip_bfloat16* __restrict__ xt,
                                                const float* __restrict__ ah, const float* __restrict__ at,
                                                float4* __restrict__ sp, float4* __restrict__ dp) {
    int lane = threadIdx.x & 63;
    int w = threadIdx.x >> 6;
    int n = blockIdx.x * 4 + w;
    if (n >= NN) return;
    float xh0 = __bfloat162float(xh[(size_t)n*KRH + lane]);
    float xh1 = __bfloat162float(xh[(size_t)n*KRH + 64 + lane]);
    float xt0 = __bfloat162float(xt[(size_t)n*KRH + lane]);
    float xt1 = __bfloat162float(xt[(size_t)n*KRH + 64 + lane]);
    float ah00 = ah[lane],       ah01 = ah[64 + lane];
    float ah10 = ah[128 + lane], ah11 = ah[192 + lane];
    float at00 = at[lane],       at01 = at[64 + lane];
    float at10 = at[128 + lane], at11 = at[192 + lane];
    float v[8];
    v[0] = xh0*ah00 + xh1*ah01;  // s_hh h0
    v[1] = xh0*ah10 + xh1*ah11;  // s_hh h1
    v[2] = xt0*ah00 + xt1*ah01;  // s_th h0
    v[3] = xt0*ah10 + xt1*ah11;  // s_th h1
    v[4] = xt0*at00 + xt1*at01;  // s_tt h0
    v[5] = xt0*at10 + xt1*at11;  // s_tt h1
    v[6] = xh0*at00 + xh1*at01;  // s_ht h0
    v[7] = xh0*at10 + xh1*at11;  // s_ht h1
    for (int off = 32; off; off >>= 1)
        for (int j = 0; j < 8; ++j) v[j] += __shfl_xor(v[j], off);
    if (lane == 0) {
        sp[n] = make_float4(v[0], v[1], v[2], v[3]);
        dp[n] = make_float4(v[4], v[5], v[6], v[7]);
    }
}

__device__ __forceinline__ float eexp(float x) {
    x = x > 0.f ? x : 0.01f * x;       // leaky_relu(0.01)
    x = fminf(x, 50.f);                // overflow guard
    return __expf(x);
}

// Per edge: 4 exp scores -> LDS-staged segment sums + per-rel histogram.
__global__ __launch_bounds__(256) void k_edge(const int* __restrict__ src, const int* __restrict__ dst,
                                              const int* __restrict__ rel,
                                              const float4* __restrict__ sp, const float4* __restrict__ dp,
                                              float* __restrict__ sums, unsigned* __restrict__ counts) {
    __shared__ float ls[NR * 4];
    __shared__ unsigned lc[NR];
    for (int i = threadIdx.x; i < NR * 4; i += 256) ls[i] = 0.f;
    for (int i = threadIdx.x; i < NR; i += 256) lc[i] = 0u;
    __syncthreads();
    int stride = gridDim.x * blockDim.x;
    for (int e = blockIdx.x * blockDim.x + threadIdx.x; e < NE; e += stride) {
        int s = clampi(src[e], NN), d = clampi(dst[e], NN), r = clampi(rel[e], NR);
        float4 a = sp[s], b = dp[d];
        atomicAdd(&ls[r*4+0], eexp(a.x + b.x));
        atomicAdd(&ls[r*4+1], eexp(a.y + b.y));
        atomicAdd(&ls[r*4+2], eexp(a.z + b.z));
        atomicAdd(&ls[r*4+3], eexp(a.w + b.w));
        atomicAdd(&lc[r], 1u);
    }
    __syncthreads();
    for (int i = threadIdx.x; i < NR * 4; i += 256)
        if (ls[i] != 0.f) atomicAdd(&sums[i], ls[i]);
    for (int i = threadIdx.x; i < NR; i += 256)
        if (lc[i]) atomicAdd(&counts[i], lc[i]);
}

// Single-block exclusive scan of counts[500] -> base, cursor.
__global__ __launch_bounds__(512) void k_scan(const unsigned* __restrict__ counts,
                                              unsigned* __restrict__ base, unsigned* __restrict__ cursor) {
    __shared__ unsigned sc[512];
    int t = threadIdx.x;
    sc[t] = (t < NR) ? counts[t] : 0u;
    __syncthreads();
    for (int off = 1; off < 512; off <<= 1) {
        unsigned add = (t >= off) ? sc[t - off] : 0u;
        __syncthreads();
        sc[t] += add;
        __syncthreads();
    }
    if (t < NR) {
        unsigned b = (t == 0) ? 0u : sc[t - 1];
        base[t] = b;
        cursor[t] = b;
    }
    if (t == NR) base[NR] = sc[NR - 1];
}

// LDS-staged counting-sort scatter: 64 blocks x 12500 edges.
#define SB 64
__global__ __launch_bounds__(256) void k_scatter(const int* __restrict__ rel,
                                                 unsigned* __restrict__ cursor, unsigned* __restrict__ elist) {
    __shared__ unsigned lh[NR];
    __shared__ unsigned lcur[NR];
    int t = threadIdx.x;
    unsigned lo = blockIdx.x * (NE / SB);
    unsigned hi = lo + (NE / SB);
    for (int i = t; i < NR; i += 256) lh[i] = 0u;
    __syncthreads();
    for (unsigned e = lo + t; e < hi; e += 256)
        atomicAdd(&lh[clampi(rel[e], NR)], 1u);
    __syncthreads();
    for (int i = t; i < NR; i += 256)
        lcur[i] = lh[i] ? atomicAdd(&cursor[i], lh[i]) : 0u;
    __syncthreads();
    for (unsigned e = lo + t; e < hi; e += 256) {
        int r = clampi(rel[e], NR);
        unsigned pos = atomicAdd(&lcur[r], 1u);
        if (pos < NE) elist[pos] = e;
    }
}

// 8 blocks/rel x 256 thr. Two-phase per 256-edge chunk (see round-5 notes).
#define PB2 8
__global__ __launch_bounds__(256) void k_acc(const int* __restrict__ src, const int* __restrict__ dst,
                                             const float4* __restrict__ sp, const float4* __restrict__ dp,
                                             const float4* __restrict__ sums4,
                                             const unsigned* __restrict__ counts, const unsigned* __restrict__ base,
                                             const unsigned* __restrict__ elist,
                                             const __hip_bfloat16* __restrict__ xh,
                                             const __hip_bfloat16* __restrict__ xt,
                                             float* __restrict__ acc) {
    __shared__ unsigned lsn[256], ldn[256];
    __shared__ float lw1[256], lw2[256];
    __shared__ float red[4][128];
    int r = blockIdx.x / PB2;
    int p = blockIdx.x % PB2;
    int t = threadIdx.x, lane = t & 63, wv = t >> 6;
    int c2 = lane * 2;
    unsigned cnt = counts[r];
    if (cnt > NE) cnt = 0;            // poison guard
    unsigned b0 = base[r];
    float4 s = sums4[r];
    float inv0 = 1.f/(s.x + 1e-16f), inv1 = 1.f/(s.y + 1e-16f);
    float inv2 = 1.f/(s.z + 1e-16f), inv3 = 1.f/(s.w + 1e-16f);
    float ax = 0.f, ay = 0.f;

    for (unsigned cb = (unsigned)p * 256u; cb < cnt; cb += PB2 * 256u) {
        unsigned cn = cnt - cb; if (cn > 256u) cn = 256u;
        __syncthreads();                      // previous chunk's readers done
        if ((unsigned)t < cn) {
            unsigned e = elist[b0 + cb + t];
            int sn = clampi(src[e], NN), dn = clampi(dst[e], NN);
            float4 av = sp[sn], bv = dp[dn];
            lsn[t] = (unsigned)sn; ldn[t] = (unsigned)dn;
            lw1[t] = eexp(av.x + bv.x) * inv0 + eexp(av.y + bv.y) * inv1;
            lw2[t] = eexp(av.z + bv.z) * inv2 + eexp(av.w + bv.w) * inv3;
        }
        __syncthreads();
        for (unsigned j = (unsigned)wv; j < cn; j += 4) {
            unsigned sn = lsn[j], dn = ldn[j];
            float w1 = lw1[j], w2 = lw2[j];
            unsigned uh = *(const unsigned*)((const unsigned short*)xh + (size_t)sn * KRH + c2);
            unsigned ut = *(const unsigned*)((const unsigned short*)xt + (size_t)dn * KRH + c2);
            float hx = __uint_as_float(uh << 16);
            float hy = __uint_as_float(uh & 0xffff0000u);
            float tx = __uint_as_float(ut << 16);
            float ty = __uint_as_float(ut & 0xffff0000u);
            ax = fmaf(w1, hx, fmaf(w2, tx, ax));
            ay = fmaf(w1, hy, fmaf(w2, ty, ay));
        }
    }
    __syncthreads();
    red[wv][c2] = ax; red[wv][c2 + 1] = ay;
    __syncthreads();
    if (wv == 0) {
        float vx = red[0][c2] + red[1][c2] + red[2][c2] + red[3][c2];
        float vy = red[0][c2+1] + red[1][c2+1] + red[2][c2+1] + red[3][c2+1];
        atomicAdd(&acc[(size_t)r * KRH + c2], vx);
        atomicAdd(&acc[(size_t)r * KRH + c2 + 1], vy);
    }
}

// Output dtype follows input dtype (reference returns x_e.dtype).
__global__ __launch_bounds__(256) void k_out(const float* __restrict__ acc,
                                             const unsigned* __restrict__ flag, void* __restrict__ out) {
    int i = blockIdx.x * 256 + threadIdx.x;
    if (i < NR * KRH) {
        float v = acc[i] * 0.25f;     // / num_heads(2) / 2
        if (!isfinite(v)) v = 0.f;    // diagnostic backstop
        if (flag[0]) ((__hip_bfloat16*)out)[i] = __float2bfloat16(v);
        else         ((float*)out)[i] = v;
    }
}

extern "C" void kernel_launch(void* const* d_in, const int* in_sizes, int n_in,
                              void* d_out, int out_size, void* d_ws, size_t ws_size,
                              hipStream_t stream) {
    const void* xe  = d_in[0];
    const int* eidx = (const int*)d_in[1];
    const int* rel  = (const int*)d_in[2];
    const void* wh  = d_in[3];
    const void* wt  = d_in[4];
    const void* ahp = d_in[5];
    const void* atp = d_in[6];

    const int* src = eidx;
    const int* dst = eidx + NE;

    char* ws = (char*)d_ws;
    __hip_bfloat16* xh = (__hip_bfloat16*)(ws + OFF_XH);
    __hip_bfloat16* xt = (__hip_bfloat16*)(ws + OFF_XT);
    float4*   sp     = (float4*)(ws + OFF_SP);
    float4*   dp     = (float4*)(ws + OFF_DP);
    float*    sums   = (float*)(ws + OFF_SUMS);
    unsigned* counts = (unsigned*)(ws + OFF_CNT);
    unsigned* basep  = (unsigned*)(ws + OFF_BASE);
    unsigned* cursor = (unsigned*)(ws + OFF_CUR);
    unsigned* elist  = (unsigned*)(ws + OFF_ELIST);
    float*    acc    = (float*)(ws + OFF_ACC);
    float*    ah32   = (float*)(ws + OFF_AH);
    float*    at32   = (float*)(ws + OFF_AT);
    unsigned* flag   = (unsigned*)(ws + OFF_FLAG);
    __bf16*   whh    = (__bf16*)(ws + OFF_WHH);
    __bf16*   whl    = (__bf16*)(ws + OFF_WHL);
    __bf16*   wth    = (__bf16*)(ws + OFF_WTH);
    __bf16*   wtl    = (__bf16*)(ws + OFF_WTL);

    k_init<<<261, 256, 0, stream>>>((const unsigned*)xe, ahp, atp, flag, ah32, at32,
                                     (unsigned*)(ws + OFF_SUMS), (unsigned*)acc);
    k_split<<<(KRH * KEH + 255) / 256, 256, 0, stream>>>(wh, wt, flag, whh, whl, wth, wtl);
    k_gemm<<<(NN + GM - 1) / GM, 256, 0, stream>>>(xe, flag, whh, whl, wth, wtl, xh, xt);
    k_scores<<<(NN + 3) / 4, 256, 0, stream>>>(xh, xt, ah32, at32, sp, dp);
    k_edge<<<512, 256, 0, stream>>>(src, dst, rel, sp, dp, sums, counts);
    k_scan<<<1, 512, 0, stream>>>(counts, basep, cursor);
    k_scatter<<<SB, 256, 0, stream>>>(rel, cursor, elist);
    k_acc<<<NR * PB2, 256, 0, stream>>>(src, dst, sp, dp, (const float4*)sums, counts, basep, elist, xh, xt, acc);
    k_out<<<(NR * KRH + 255) / 256, 256, 0, stream>>>(acc, flag, d_out);
}